// Round 4
// baseline (454.403 us; speedup 1.0000x reference)
//
#include <hip/hip_runtime.h>

#define HB  20
#define DD  40
#define BPW 3              // batches per wave (3 x 20 lanes = 60 of 64)
#define WAVES 4            // waves per block (256 threads)
#define BPB (BPW*WAVES)    // 12 batches per block
#define HROWS 5            // J rows per emission phase (half-quarter)
#define HF (HROWS*DD)      // 200 floats per batch-phase
#define TILE_F (BPW*HF)    // 600 floats per wave tile

typedef float f32x4 __attribute__((ext_vector_type(4)));

__device__ __forceinline__ float fast_tanh(float x){
    // tanh(x) = 1 - 2/(exp(2x)+1); exact at +-inf, ~1e-7 rel error
    float e = __expf(2.0f*x);
    return 1.0f - 2.0f*__builtin_amdgcn_rcpf(e + 1.0f);
}

// Wave-local LDS visibility fence: all LDS handoff below is within one wave,
// so an in-order lgkmcnt drain suffices (no vmcnt drain -> global stores keep
// streaming). sched_barrier(0) stops hipcc hoisting dependent ops (rule #18).
__device__ __forceinline__ void wave_lds_fence(){
    asm volatile("s_waitcnt lgkmcnt(0)" ::: "memory");
    __builtin_amdgcn_sched_barrier(0);
}

// Occupancy target: 7 blocks/CU (28 waves/CU, 7 waves/SIMD).
// Requires VGPR<=64 (waves/SIMD steps at 64/128/256) and LDS<=22528B/block.
__global__ __launch_bounds__(256, 7)
void ende_kernel(const float* __restrict__ src,
                 const float* __restrict__ w1,
                 const float* __restrict__ w2,
                 const float* __restrict__ w3g,
                 const float* __restrict__ w4g,
                 float* __restrict__ dout,
                 int NB)
{
    __shared__ float2 w12[HB*21];            // (w1,w2) row-padded, block-wide (3360B)
    __shared__ float2 w34[HB*21];            // (w3,w4) row-padded, block-wide (3360B)
    __shared__ float  xs [WAVES][BPW][DD];   // per-wave x; p2 half reused for s2 (1920B)
    __shared__ float2 aps[WAVES][BPW][HB];   // (a1,a2) per-wave (1920B)
    __shared__ float2 bps[WAVES][BPW][HB];   // (b1,b2) per-wave (1920B)
    __shared__ __align__(16) float tile[WAVES][TILE_F];  // J staging (9600B)
    // total: 22080 B -> 7 blocks/CU on 160KiB LDS

    const int t    = threadIdx.x;
    const int wv   = t >> 6;
    const int lane = t & 63;
    const bool act = lane < (BPW*HB);
    const int sub  = lane / HB;          // batch within wave
    const int j    = lane % HB;          // owned column
    const int batch0 = blockIdx.x * BPB + wv * BPW;
    const int b    = batch0 + sub;
    const bool valid = act && (b < NB);

    // ---- stage weights (block-wide) ----
    for (int q = t; q < HB*HB; q += 256){
        int i = q / HB, m = q - i*HB;
        w12[i*21+m] = make_float2(w1[q],  w2[q]);
        w34[i*21+m] = make_float2(w3g[q], w4g[q]);
    }
    // ---- stage x for this wave's batches ----
    {
        int base = batch0 * DD, lim = NB * DD;
        for (int l = lane; l < BPW*DD; l += 64){
            int g = base + l;
            if (g < lim) (&xs[wv][0][0])[l] = src[g];
        }
    }
    __syncthreads();   // the ONLY block barrier: w12/w34 are block-wide

    float e2 = 0.f, s2 = 0.f, e4 = 0.f, t1 = 0.f;

    // ---- stage 1a: f1,f2,e2,s2,(a1,a2) ----
    if (act){
        float acc1 = 0.f, acc2 = 0.f;
        #pragma unroll
        for (int m = 0; m < HB; m++){
            float2 w = w12[j*21+m];
            float  p = xs[wv][sub][m];          // p1 half only
            acc1 = fmaf(p, w.x, acc1);
            acc2 = fmaf(p, w.y, acc2);
        }
        float f1 = fast_tanh(acc1);
        float f2 = fast_tanh(acc2);
        e2 = __expf(f2);
        float p2  = xs[wv][sub][HB+j];          // own lane's p2 slot
        float p2e = p2 * e2;
        s2 = p2e + f1;
        xs[wv][sub][HB+j] = s2;                 // s2 overwrites consumed p2 slot
        aps[wv][sub][j] = make_float2(1.0f - f1*f1, p2e*(1.0f - f2*f2));
    }
    wave_lds_fence();   // s2 (in xs) / aps visible within the wave

    // ---- stage 1b: f3,f4,e4,t1,(b1,b2) ----
    if (act){
        float acc3 = 0.f, acc4 = 0.f;
        #pragma unroll
        for (int m = 0; m < HB; m++){
            float2 w = w34[j*21+m];
            float  s = xs[wv][sub][HB+m];       // s2 lives in p2 half
            acc3 = fmaf(s, w.x, acc3);
            acc4 = fmaf(s, w.y, acc4);
        }
        float f3 = fast_tanh(acc3);
        float f4 = fast_tanh(acc4);
        e4 = __expf(f4);
        float p1  = xs[wv][sub][j];
        float s1e = p1 * e4;
        t1 = s1e + f3;
        bps[wv][sub][j] = make_float2(1.0f - f3*f3, s1e*(1.0f - f4*f4));
    }

    // ---- J21 column j (aps fenced before stage 1b; not rewritten) ----
    float cj[HB];
    if (act){
        #pragma unroll
        for (int k = 0; k < HB; k++){
            float2 a = aps[wv][sub][k];
            float2 w = w12[k*21+j];
            cj[k] = a.x*w.x + a.y*w.y;
        }
    }

    // ---- out vector ----
    if (valid){
        dout[b*DD + j]      = t1;
        dout[b*DD + HB + j] = s2;
    }
    wave_lds_fence();   // bps visible within the wave

    float* __restrict__ Jq = dout + (size_t)NB*DD + (size_t)batch0*(DD*DD);

    // emission: 150 float4 per phase (3 subs x 50); lane map recomputed (saves VGPRs)
    auto emit_phase = [&](int h){
        wave_lds_fence();   // tile writes visible to this wave's emission lanes
        #pragma unroll
        for (int it = 0; it < 3; it++){
            int v  = lane + 64*it;
            int se = v / 50;
            int eoff = (v - se*50) * 4;
            if (v < 150 && (batch0 + se) < NB){
                f32x4 val = *(const f32x4*)&tile[wv][se*HF + eoff];
                *(f32x4*)&Jq[(size_t)se*(DD*DD) + h*HF + eoff] = val;
            }
        }
        wave_lds_fence();   // emission reads drained before tile is overwritten
    };

    // ---- phases 0..3: TL/TR rows (FMA-heavy) ----
    #pragma unroll
    for (int h = 0; h < 4; h++){
        if (valid){
            #pragma unroll
            for (int r = 0; r < HROWS; r++){
                const int i = h*HROWS + r;     // compile-time (h,r unrolled)
                float s3 = 0.f, s4 = 0.f;
                #pragma unroll
                for (int k = 0; k < HB; k++){
                    s3 = fmaf(w3g[i*HB+k], cj[k], s3);   // wave-uniform -> s_load
                    s4 = fmaf(w4g[i*HB+k], cj[k], s4);
                }
                float2 bb = bps[wv][sub][i];
                float2 wc = w34[i*21+j];
                tile[wv][sub*HF + r*DD + j]      = bb.x*s3 + bb.y*s4 + ((i == j) ? e4 : 0.0f);
                tile[wv][sub*HF + r*DD + HB + j] = (bb.x*wc.x + bb.y*wc.y) * e2;
            }
        }
        emit_phase(h);
    }

    // ---- phases 4..7: BL/BR rows (register copies) ----
    #pragma unroll
    for (int h = 4; h < 8; h++){
        if (valid){
            #pragma unroll
            for (int r = 0; r < HROWS; r++){
                const int rr = (h-4)*HROWS + r;
                tile[wv][sub*HF + r*DD + j]      = cj[rr];
                tile[wv][sub*HF + r*DD + HB + j] = (rr == j) ? e2 : 0.0f;
            }
        }
        emit_phase(h);
    }
}

extern "C" void kernel_launch(void* const* d_in, const int* in_sizes, int n_in,
                              void* d_out, int out_size, void* d_ws, size_t ws_size,
                              hipStream_t stream)
{
    const float* src = (const float*)d_in[0];
    const float* w1  = (const float*)d_in[1];
    const float* w2  = (const float*)d_in[2];
    const float* w3  = (const float*)d_in[3];
    const float* w4  = (const float*)d_in[4];
    float* out = (float*)d_out;
    int NB = in_sizes[0] / DD;
    int grid = (NB + BPB - 1) / BPB;
    hipLaunchKernelGGL(ende_kernel, dim3(grid), dim3(256), 0, stream,
                       src, w1, w2, w3, w4, out, NB);
}